// Round 7
// baseline (160.819 us; speedup 1.0000x reference)
//
#include <hip/hip_runtime.h>
#include <hip/hip_bf16.h>
#include <math.h>

// B=1024, N=22, F_IN=32, T=32, K=3, CHEV=64, TIMEF=64
// x[b,n,f,t]: b-stride 22528, n-stride 1024, f-stride 32

typedef unsigned short u16;
typedef __attribute__((ext_vector_type(8))) short short8;
typedef __attribute__((ext_vector_type(16))) float f32x16;
typedef __attribute__((ext_vector_type(2))) float f32x2;

__device__ __forceinline__ float sigm(float v){ return 1.f/(1.f+expf(-v)); }

__device__ __forceinline__ u16 f2bf(float x){
  __hip_bfloat16 h = __float2bfloat16(x);
  return *reinterpret_cast<u16*>(&h);
}
__device__ __forceinline__ unsigned f2bf2(float lo, float hi){
  return (unsigned)f2bf(lo) | ((unsigned)f2bf(hi) << 16);
}

// ---------------- K_prep (blocks 0..80, 32x32-MFMA fragment packing) + supports (block 81) ----
__global__ void k_sup_prep(const float* __restrict__ emb, float* __restrict__ wsT,
                           const float* __restrict__ Theta,
                           const float* __restrict__ tw, const float* __restrict__ tb,
                           const float* __restrict__ rw, const float* __restrict__ rb,
                           u16* __restrict__ thA, u16* __restrict__ wA, float* __restrict__ wsB){
  if (blockIdx.x < 81){
    int tid = blockIdx.x*256 + threadIdx.x;
    if (tid < 6144){
      // thA32[(fb*2+ch)*512 + l*8 + j] = Theta[row][32ch + (l&31)]
      // fb 0..3: row = 32 + 16*fb + 8*(l>>5) + j   (Theta_1, Theta_2 : K=64 part)
      // fb 4,5 : row = 16*(fb-4) + 8*(l>>5) + j    (Theta_0 : K=32 x-part)
      int j = tid&7, l = (tid>>3)&63, slot = tid>>9;   // slot 0..11
      int fb = slot>>1, ch = slot&1;
      int hi = l>>5, r = l&31;
      int row = (fb < 4) ? (32 + 16*fb + 8*hi + j) : (16*(fb-4) + 8*hi + j);
      thA[tid] = f2bf(Theta[row*64 + 32*ch + r]);
    } else if (tid < 20480){
      // wA32[(kb*2+oh)*512 + l*8 + j] = Wmat[16kb + 8*(l>>5)+j][32oh + (l&31)]
      int e = tid - 6144;
      int j = e&7, l = (e>>3)&63, slot = e>>9;         // slot 0..27
      int kb = slot>>1, oh = slot&1;
      int hi = l>>5, r = l&31;
      int k = 16*kb + 8*hi + j;
      int o = 32*oh + r;
      float v = (k < 192) ? tw[o*192 + (k&63)*3 + (k>>6)] : rw[o*32 + (k-192)];
      wA[e] = f2bf(v);
    } else if (tid < 20544){
      int o = tid - 20480; wsB[o] = tb[o] + rb[o];
    }
    return;
  }
  // block 81: Chebyshev supports
  __shared__ float M[484];
  __shared__ float T1s[484];
  int tid = threadIdx.x;
  for (int idx=tid; idx<484; idx+=256){
    int n = idx/22, m = idx - (idx/22)*22;
    float s = 0.f;
    for (int j=0;j<22;j++) s += emb[n*22+j]*emb[m*22+j];
    M[idx] = fmaxf(s, 0.f);
  }
  __syncthreads();
  if (tid < 22){
    float mx = -1e30f;
    for (int m=0;m<22;m++) mx = fmaxf(mx, M[tid*22+m]);
    float s = 0.f;
    for (int m=0;m<22;m++) s += expf(M[tid*22+m]-mx);
    float inv = 1.f/s;
    for (int m=0;m<22;m++) T1s[tid*22+m] = expf(M[tid*22+m]-mx)*inv;
  }
  __syncthreads();
  for (int idx=tid; idx<484; idx+=256){
    int n = idx/22, m = idx - (idx/22)*22;
    float s = 0.f;
    for (int p=0;p<22;p++) s += T1s[n*22+p]*T1s[p*22+m];
    wsT[idx]      = T1s[idx];
    wsT[484+idx]  = 2.f*s - ((n==m)?1.f:0.f);
  }
}

// ---------------- K12: temporal + spatial attention -> S_norm (512 threads) ----
__global__ __launch_bounds__(512) void k_attn(
    const float* __restrict__ x,
    const float* __restrict__ U1, const float* __restrict__ U2, const float* __restrict__ U3,
    const float* __restrict__ be, const float* __restrict__ Ve,
    const float* __restrict__ W1, const float* __restrict__ W2, const float* __restrict__ W3,
    const float* __restrict__ bs, const float* __restrict__ Vs,
    float* __restrict__ snorm){
  int b = blockIdx.x, tid = threadIdx.x;
  const float* xb = x + (size_t)b*22528;
  __shared__ float xu1[1024];
  __shared__ float rhs_t[704];
  __shared__ float lhs_t[704];
  __shared__ float sigp[1024];
  __shared__ float Em[1024];
  __shared__ float sm[1024];
  __shared__ float w1e[32];
  __shared__ float xw3[704];
  __shared__ float lhsS[704];
  __shared__ float lhs2[704];
  __shared__ float rhsS[704];
  __shared__ float sig2[484];
  __shared__ float Sl[484];

  for (int idx=tid; idx<1024; idx+=512){
    float a=0.f;
    for (int n=0;n<22;n++) a = fmaf(xb[n*1024 + idx], U1[n], a);
    xu1[idx]=a;
  }
  for (int idx=tid; idx<704; idx+=512){
    int n = idx>>5, t = idx&31; float a=0.f, c=0.f;
    for (int f=0;f<32;f++){ float xv = xb[n*1024+f*32+t]; a = fmaf(U3[f],xv,a); c = fmaf(W3[f],xv,c); }
    rhs_t[idx]=a; xw3[idx]=c;
  }
  __syncthreads();
  for (int idx=tid; idx<704; idx+=512){
    int t = idx/22, n2 = idx - t*22; float a=0.f;
    for (int f=0;f<32;f++) a = fmaf(xu1[f*32+t], U2[f*22+n2], a);
    lhs_t[idx]=a;
  }
  __syncthreads();
  for (int idx=tid; idx<1024; idx+=512){
    int s = idx>>5, u = idx&31; float p=0.f;
    for (int n=0;n<22;n++) p = fmaf(lhs_t[s*22+n], rhs_t[n*32+u], p);
    sigp[idx] = sigm(p + be[idx]);
  }
  __syncthreads();
  for (int idx=tid; idx<1024; idx+=512){
    int t = idx>>5, u = idx&31; float a=0.f;
    for (int s2=0;s2<32;s2++) a = fmaf(Ve[t*32+s2], sigp[s2*32+u], a);
    Em[idx]=a;
  }
  __syncthreads();
  {
    int u = tid>>4, th = tid&15;
    float e0 = Em[(2*th)*32 + u], e1 = Em[(2*th+1)*32 + u];
    float mx = fmaxf(e0, e1);
    #pragma unroll
    for (int mask=1; mask<16; mask<<=1) mx = fmaxf(mx, __shfl_xor(mx, mask));
    float x0 = expf(e0-mx), x1 = expf(e1-mx);
    float s = x0 + x1;
    #pragma unroll
    for (int mask=1; mask<16; mask<<=1) s += __shfl_xor(s, mask);
    float inv = 1.f/s;
    sm[(2*th)*32 + u]   = x0*inv;
    sm[(2*th+1)*32 + u] = x1*inv;
  }
  __syncthreads();
  {
    int u = tid>>4, th = tid&15;
    float pw = fmaf(sm[u*32 + 2*th], W1[2*th], sm[u*32 + 2*th+1]*W1[2*th+1]);
    #pragma unroll
    for (int mask=1; mask<16; mask<<=1) pw += __shfl_xor(pw, mask);
    if (th==0) w1e[u] = pw;
  }
  __syncthreads();
  for (int idx=tid; idx<704; idx+=512){
    int n = idx>>5, f = idx&31; float a=0.f;
    for (int u=0;u<32;u++) a = fmaf(xb[n*1024+f*32+u], w1e[u], a);
    lhsS[idx]=a;
  }
  __syncthreads();
  for (int idx=tid; idx<704; idx+=512){
    int n = idx>>5, t = idx&31; float a=0.f;
    for (int f=0;f<32;f++) a = fmaf(lhsS[n*32+f], W2[f*32+t], a);
    lhs2[idx]=a;
  }
  for (int idx=tid; idx<704; idx+=512){
    int mm = idx>>5, t = idx&31; float a=0.f;
    for (int u=0;u<32;u++) a = fmaf(xw3[mm*32+u], sm[u*32+t], a);
    rhsS[idx]=a;
  }
  __syncthreads();
  for (int idx=tid; idx<484; idx+=512){
    int a_ = idx/22, l = idx - (idx/22)*22; float p=0.f;
    for (int t=0;t<32;t++) p = fmaf(lhs2[a_*32+t], rhsS[l*32+t], p);
    sig2[idx] = sigm(p + bs[idx]);
  }
  __syncthreads();
  for (int idx=tid; idx<484; idx+=512){
    int n = idx/22, l = idx - (idx/22)*22; float s=0.f;
    for (int mm=0;mm<22;mm++) s = fmaf(Vs[n*22+mm], sig2[mm*22+l], s);
    Sl[idx]=s;
  }
  __syncthreads();
  {
    int grp = tid>>5, nn = tid&31;
    for (int l = grp; l < 22; l += 16){
      float v = (nn<22) ? Sl[nn*22 + l] : -1e30f;
      float mx = v;
      #pragma unroll
      for (int mask=1; mask<32; mask<<=1) mx = fmaxf(mx, __shfl_xor(mx, mask));
      float e = (nn<22) ? expf(v-mx) : 0.f;
      float s = e;
      #pragma unroll
      for (int mask=1; mask<32; mask<<=1) s += __shfl_xor(s, mask);
      if (nn<22) snorm[(size_t)b*484 + nn*22 + l] = e*(1.f/s);
    }
  }
}

// ---------------- Fused m-pair (32x32x16 MFMA): cheb + Theta GEMM + conv GEMM + LN ----
// Wave w: mi = w>>1, half = w&1. Per-wave B-operand LDS reads halve vs 16x16 tiles.
// Phase A: thread owns (t, 4 consecutive f) -> all LDS writes are b64 row-contiguous.
__global__ __launch_bounds__(256, 5) void k_fused(
    const float* __restrict__ x,
    const float* __restrict__ wsT, const float* __restrict__ snorm,
    const u16* __restrict__ thA, const u16* __restrict__ wA, const float* __restrict__ wsB,
    const float* __restrict__ lng, const float* __restrict__ lnb,
    float* __restrict__ out){
  __shared__ __align__(16) u16 GtU[2][32*72];   // G^T bf16 [t][k1*32+f], stride 72
  __shared__ __align__(16) u16 sgTU[2][34*72];  // sg^T bf16 [t+1][c], rows 0,33 zero (cols 0..63)
  __shared__ __align__(16) u16 xTU[2][32*40];   // x[m]^T bf16 [t][f], stride 40
  __shared__ __align__(16) float ak4[22*4];     // [n][mi*2+k1]
  __shared__ float smm[2];

  int wg = blockIdx.x;
  int logical = (wg & 7)*1408 + (wg >> 3);      // 11264 = 8*1408 XCD swizzle
  int b = logical/11, mp = logical - b*11;
  int m0 = mp*2;
  int tid = threadIdx.x;
  const float* xb = x + (size_t)b*22528;

  if (tid < 128){                                // zero sg pad rows 0, 33 (data cols 0..63)
    int mi = tid>>6, c = tid&63;
    sgTU[mi][c] = 0;
    sgTU[mi][33*72 + c] = 0;
  }
  if (tid < 88){
    int n = tid>>2, j = tid&3;                  // j = mi*2 + k1
    int mi = j>>1, k1 = j&1;
    int m = m0 + mi;
    ak4[tid] = wsT[k1*484 + n*22 + m] * snorm[(size_t)b*484 + n*22 + m];
  }
  if (tid < 2) smm[tid] = snorm[(size_t)b*484 + (m0+tid)*23];
  __syncthreads();

  int t32 = tid&31;

  // ---- Phase A: G[k1][f][t] = sum_n ak*x, thread = (t, f0..f0+3) ----
  {
    int fq = tid>>5, f0 = fq*4;
    const float* xt = xb + f0*32 + t32;
    f32x2 acc[4][2];                             // [mi*2+k1][pair]
    #pragma unroll
    for (int j=0;j<4;j++){ acc[j][0]=f32x2{0,0}; acc[j][1]=f32x2{0,0}; }
    #pragma unroll 2
    for (int n=0;n<22;n++){
      float4 av = *(const float4*)&ak4[n*4];
      const float* p = xt + n*1024;
      float x0 = p[0], x1 = p[32], x2 = p[64], x3 = p[96];
      f32x2 lo = {x0,x1}, hi2 = {x2,x3};
      f32x2 c0 = {av.x,av.x}, c1 = {av.y,av.y}, c2 = {av.z,av.z}, c3 = {av.w,av.w};
      acc[0][0] = __builtin_elementwise_fma(c0, lo,  acc[0][0]);
      acc[0][1] = __builtin_elementwise_fma(c0, hi2, acc[0][1]);
      acc[1][0] = __builtin_elementwise_fma(c1, lo,  acc[1][0]);
      acc[1][1] = __builtin_elementwise_fma(c1, hi2, acc[1][1]);
      acc[2][0] = __builtin_elementwise_fma(c2, lo,  acc[2][0]);
      acc[2][1] = __builtin_elementwise_fma(c2, hi2, acc[2][1]);
      acc[3][0] = __builtin_elementwise_fma(c3, lo,  acc[3][0]);
      acc[3][1] = __builtin_elementwise_fma(c3, hi2, acc[3][1]);
    }
    #pragma unroll
    for (int mi=0;mi<2;mi++){
      #pragma unroll
      for (int k1=0;k1<2;k1++){
        int j = mi*2 + k1;
        uint2 v; v.x = f2bf2(acc[j][0][0], acc[j][0][1]); v.y = f2bf2(acc[j][1][0], acc[j][1][1]);
        *(uint2*)&GtU[mi][t32*72 + k1*32 + f0] = v;
      }
      const float* q = xb + (m0+mi)*1024 + f0*32 + t32;
      float y0 = q[0], y1 = q[32], y2 = q[64], y3 = q[96];
      uint2 v; v.x = f2bf2(y0,y1); v.y = f2bf2(y2,y3);
      *(uint2*)&xTU[mi][t32*40 + f0] = v;
    }
  }
  __syncthreads();

  int w = tid>>6, l = tid&63, hi = l>>5;
  int mi = w>>1, ch = w&1;
  int lt = l&31;

  // ---- Phase B: sg[c][t] = relu( Theta12^T G + smm * Theta0^T x ), c-half = ch ----
  {
    f32x16 aG, aX;
    #pragma unroll
    for (int i=0;i<16;i++){ aG[i]=0.f; aX[i]=0.f; }
    const u16* gRow = &GtU[mi][lt*72 + 8*hi];
    const u16* xRow = &xTU[mi][lt*40 + 8*hi];
    #pragma unroll
    for (int fb=0; fb<4; ++fb){
      short8 a = *(const short8*)(thA + (size_t)(fb*2+ch)*512 + l*8);
      aG = __builtin_amdgcn_mfma_f32_32x32x16_bf16(a, *(const short8*)(gRow + 16*fb), aG, 0,0,0);
    }
    #pragma unroll
    for (int fb=4; fb<6; ++fb){
      short8 a = *(const short8*)(thA + (size_t)(fb*2+ch)*512 + l*8);
      aX = __builtin_amdgcn_mfma_f32_32x32x16_bf16(a, *(const short8*)(xRow + 16*(fb-4)), aX, 0,0,0);
    }
    float smv = smm[mi];
    u16* srow = &sgTU[mi][(1+lt)*72 + ch*32 + 4*hi];
    #pragma unroll
    for (int q=0;q<4;q++){
      float v0 = fmaxf(fmaf(smv, aX[4*q+0], aG[4*q+0]), 0.f);
      float v1 = fmaxf(fmaf(smv, aX[4*q+1], aG[4*q+1]), 0.f);
      float v2 = fmaxf(fmaf(smv, aX[4*q+2], aG[4*q+2]), 0.f);
      float v3 = fmaxf(fmaf(smv, aX[4*q+3], aG[4*q+3]), 0.f);
      uint2 pv; pv.x = f2bf2(v0,v1); pv.y = f2bf2(v2,v3);
      *(uint2*)&srow[8*q] = pv;
    }
  }
  __syncthreads();

  // ---- Phase C: y[o][t] = sum_k W[k][o]*B[k][t], K=224, o-half = ch ----
  f32x16 acc;
  #pragma unroll
  for (int i=0;i<16;i++) acc[i]=0.f;
  {
    #pragma unroll
    for (int kb=0; kb<12; ++kb){
      int dt = kb>>2, cq = kb&3;
      short8 wk = *(const short8*)(wA + (size_t)(kb*2+ch)*512 + l*8);
      const short8* Bp = (const short8*)&sgTU[mi][(lt+dt)*72 + cq*16 + 8*hi];
      acc = __builtin_amdgcn_mfma_f32_32x32x16_bf16(wk, *Bp, acc, 0,0,0);
    }
    #pragma unroll
    for (int kb=12; kb<14; ++kb){
      short8 wk = *(const short8*)(wA + (size_t)(kb*2+ch)*512 + l*8);
      const short8* Bp = (const short8*)&xTU[mi][lt*40 + (kb-12)*16 + 8*hi];
      acc = __builtin_amdgcn_mfma_f32_32x32x16_bf16(wk, *Bp, acc, 0,0,0);
    }
  }

  // ---- Epilogue: bias + relu + LN over o (64) per t ----
  float y[16];
  float s1 = 0.f, s2 = 0.f;
  {
    const float4* wsB4 = (const float4*)wsB;
    #pragma unroll
    for (int q=0;q<4;q++){
      float4 bq = wsB4[8*ch + 2*q + hi];
      float bb[4] = {bq.x, bq.y, bq.z, bq.w};
      #pragma unroll
      for (int e=0;e<4;e++){
        float v = fmaxf(acc[4*q+e] + bb[e], 0.f);
        y[4*q+e] = v;
        s1 += v;
        s2 = fmaf(v, v, s2);
      }
    }
  }
  s1 += __shfl_xor(s1, 32);
  s2 += __shfl_xor(s2, 32);
  float* p1 = (float*)&GtU[0][0];    // overlay (GtU dead after Phase B): [2mi*32t][2ch]
  float* p2 = p1 + 128;
  if (l < 32){
    p1[(mi*32 + lt)*2 + ch] = s1;
    p2[(mi*32 + lt)*2 + ch] = s2;
  }
  __syncthreads();
  f32x2 q1 = *(const f32x2*)&p1[(mi*32 + lt)*2];
  f32x2 q2 = *(const f32x2*)&p2[(mi*32 + lt)*2];
  float S1 = q1[0] + q1[1], S2 = q2[0] + q2[1];
  float mu = S1*(1.f/64.f);
  float var = S2*(1.f/64.f) - mu*mu;
  float rs = rsqrtf(var + 1e-5f);
  {
    const float4* lng4 = (const float4*)lng;
    const float4* lnb4 = (const float4*)lnb;
    float* ob = out + ((size_t)(b*22 + m0 + mi)*64 + 32*ch)*32;
    #pragma unroll
    for (int q=0;q<4;q++){
      float4 g4 = lng4[8*ch + 2*q + hi];
      float4 b4 = lnb4[8*ch + 2*q + hi];
      float gg[4] = {g4.x,g4.y,g4.z,g4.w};
      float bg[4] = {b4.x,b4.y,b4.z,b4.w};
      #pragma unroll
      for (int e=0;e<4;e++){
        int orow = 8*q + 4*hi + e;
        ob[orow*32 + lt] = (y[4*q+e]-mu)*rs*gg[e] + bg[e];
      }
    }
  }
}

extern "C" void kernel_launch(void* const* d_in, const int* in_sizes, int n_in,
                              void* d_out, int out_size, void* d_ws, size_t ws_size,
                              hipStream_t stream){
  const float* x     = (const float*)d_in[0];
  const float* U1    = (const float*)d_in[1];
  const float* U2    = (const float*)d_in[2];
  const float* U3    = (const float*)d_in[3];
  const float* be    = (const float*)d_in[4];
  const float* Ve    = (const float*)d_in[5];
  const float* W1    = (const float*)d_in[6];
  const float* W2    = (const float*)d_in[7];
  const float* W3    = (const float*)d_in[8];
  const float* bs    = (const float*)d_in[9];
  const float* Vs    = (const float*)d_in[10];
  const float* Theta = (const float*)d_in[11];
  const float* emb   = (const float*)d_in[12];
  const float* tw    = (const float*)d_in[13];
  const float* tb    = (const float*)d_in[14];
  const float* rw    = (const float*)d_in[15];
  const float* rb    = (const float*)d_in[16];
  const float* lng   = (const float*)d_in[17];
  const float* lnb   = (const float*)d_in[18];
  float* out = (float*)d_out;
  float* wsf = (float*)d_ws;
  float* wsT   = wsf;                        // 968 floats (pad to 1024)
  float* snorm = wsf + 1024;                 // 1024*484 floats
  u16*   thA   = (u16*)(wsf + 496640);       // 6144 u16
  u16*   wA    = (u16*)(wsf + 499712);       // 14336 u16
  float* wsB   = wsf + 506880;               // 64 floats

  k_sup_prep<<<82, 256, 0, stream>>>(emb, wsT, Theta, tw, tb, rw, rb, thA, wA, wsB);
  k_attn<<<1024, 512, 0, stream>>>(x, U1,U2,U3, be,Ve, W1,W2,W3, bs,Vs, snorm);
  k_fused<<<1024*11, 256, 0, stream>>>(x, wsT, snorm, thA, wA, wsB, lng, lnb, out);
}

// Round 8
// 157.747 us; speedup vs baseline: 1.0195x; 1.0195x over previous
//
#include <hip/hip_runtime.h>
#include <hip/hip_bf16.h>
#include <math.h>

// B=1024, N=22, F_IN=32, T=32, K=3, CHEV=64, TIMEF=64
// x[b,n,f,t]: b-stride 22528, n-stride 1024, f-stride 32

typedef unsigned short u16;
typedef __attribute__((ext_vector_type(8))) short short8;
typedef __attribute__((ext_vector_type(16))) float f32x16;
typedef __attribute__((ext_vector_type(2))) float f32x2;

__device__ __forceinline__ float sigm(float v){ return 1.f/(1.f+expf(-v)); }

__device__ __forceinline__ u16 f2bf(float x){
  __hip_bfloat16 h = __float2bfloat16(x);
  return *reinterpret_cast<u16*>(&h);
}
__device__ __forceinline__ unsigned f2bf2(float lo, float hi){
  return (unsigned)f2bf(lo) | ((unsigned)f2bf(hi) << 16);
}

// ---------------- K_prep (blocks 0..80, 32x32-MFMA fragment packing) + supports (block 81) ----
__global__ void k_sup_prep(const float* __restrict__ emb, float* __restrict__ wsT,
                           const float* __restrict__ Theta,
                           const float* __restrict__ tw, const float* __restrict__ tb,
                           const float* __restrict__ rw, const float* __restrict__ rb,
                           u16* __restrict__ thA, u16* __restrict__ wA, float* __restrict__ wsB){
  if (blockIdx.x < 81){
    int tid = blockIdx.x*256 + threadIdx.x;
    if (tid < 6144){
      // thA32[(fb*2+ch)*512 + l*8 + j] = Theta[row][32ch + (l&31)]
      // fb 0..3: row = 32 + 16*fb + 8*(l>>5) + j   (Theta_1, Theta_2 : K=64 part)
      // fb 4,5 : row = 16*(fb-4) + 8*(l>>5) + j    (Theta_0 : K=32 x-part)
      int j = tid&7, l = (tid>>3)&63, slot = tid>>9;   // slot 0..11
      int fb = slot>>1, ch = slot&1;
      int hi = l>>5, r = l&31;
      int row = (fb < 4) ? (32 + 16*fb + 8*hi + j) : (16*(fb-4) + 8*hi + j);
      thA[tid] = f2bf(Theta[row*64 + 32*ch + r]);
    } else if (tid < 20480){
      // wA32[(kb*2+oh)*512 + l*8 + j] = Wmat[16kb + 8*(l>>5)+j][32oh + (l&31)]
      int e = tid - 6144;
      int j = e&7, l = (e>>3)&63, slot = e>>9;         // slot 0..27
      int kb = slot>>1, oh = slot&1;
      int hi = l>>5, r = l&31;
      int k = 16*kb + 8*hi + j;
      int o = 32*oh + r;
      float v = (k < 192) ? tw[o*192 + (k&63)*3 + (k>>6)] : rw[o*32 + (k-192)];
      wA[e] = f2bf(v);
    } else if (tid < 20544){
      int o = tid - 20480; wsB[o] = tb[o] + rb[o];
    }
    return;
  }
  // block 81: Chebyshev supports
  __shared__ float M[484];
  __shared__ float T1s[484];
  int tid = threadIdx.x;
  for (int idx=tid; idx<484; idx+=256){
    int n = idx/22, m = idx - (idx/22)*22;
    float s = 0.f;
    for (int j=0;j<22;j++) s += emb[n*22+j]*emb[m*22+j];
    M[idx] = fmaxf(s, 0.f);
  }
  __syncthreads();
  if (tid < 22){
    float mx = -1e30f;
    for (int m=0;m<22;m++) mx = fmaxf(mx, M[tid*22+m]);
    float s = 0.f;
    for (int m=0;m<22;m++) s += expf(M[tid*22+m]-mx);
    float inv = 1.f/s;
    for (int m=0;m<22;m++) T1s[tid*22+m] = expf(M[tid*22+m]-mx)*inv;
  }
  __syncthreads();
  for (int idx=tid; idx<484; idx+=256){
    int n = idx/22, m = idx - (idx/22)*22;
    float s = 0.f;
    for (int p=0;p<22;p++) s += T1s[n*22+p]*T1s[p*22+m];
    wsT[idx]      = T1s[idx];
    wsT[484+idx]  = 2.f*s - ((n==m)?1.f:0.f);
  }
}

// ---------------- K12: temporal + spatial attention -> S_norm (512 threads) ----
__global__ __launch_bounds__(512) void k_attn(
    const float* __restrict__ x,
    const float* __restrict__ U1, const float* __restrict__ U2, const float* __restrict__ U3,
    const float* __restrict__ be, const float* __restrict__ Ve,
    const float* __restrict__ W1, const float* __restrict__ W2, const float* __restrict__ W3,
    const float* __restrict__ bs, const float* __restrict__ Vs,
    float* __restrict__ snorm){
  int b = blockIdx.x, tid = threadIdx.x;
  const float* xb = x + (size_t)b*22528;
  __shared__ float xu1[1024];
  __shared__ float rhs_t[704];
  __shared__ float lhs_t[704];
  __shared__ float sigp[1024];
  __shared__ float Em[1024];
  __shared__ float sm[1024];
  __shared__ float w1e[32];
  __shared__ float xw3[704];
  __shared__ float lhsS[704];
  __shared__ float lhs2[704];
  __shared__ float rhsS[704];
  __shared__ float sig2[484];
  __shared__ float Sl[484];

  for (int idx=tid; idx<1024; idx+=512){
    float a=0.f;
    for (int n=0;n<22;n++) a = fmaf(xb[n*1024 + idx], U1[n], a);
    xu1[idx]=a;
  }
  for (int idx=tid; idx<704; idx+=512){
    int n = idx>>5, t = idx&31; float a=0.f, c=0.f;
    for (int f=0;f<32;f++){ float xv = xb[n*1024+f*32+t]; a = fmaf(U3[f],xv,a); c = fmaf(W3[f],xv,c); }
    rhs_t[idx]=a; xw3[idx]=c;
  }
  __syncthreads();
  for (int idx=tid; idx<704; idx+=512){
    int t = idx/22, n2 = idx - t*22; float a=0.f;
    for (int f=0;f<32;f++) a = fmaf(xu1[f*32+t], U2[f*22+n2], a);
    lhs_t[idx]=a;
  }
  __syncthreads();
  for (int idx=tid; idx<1024; idx+=512){
    int s = idx>>5, u = idx&31; float p=0.f;
    for (int n=0;n<22;n++) p = fmaf(lhs_t[s*22+n], rhs_t[n*32+u], p);
    sigp[idx] = sigm(p + be[idx]);
  }
  __syncthreads();
  for (int idx=tid; idx<1024; idx+=512){
    int t = idx>>5, u = idx&31; float a=0.f;
    for (int s2=0;s2<32;s2++) a = fmaf(Ve[t*32+s2], sigp[s2*32+u], a);
    Em[idx]=a;
  }
  __syncthreads();
  {
    int u = tid>>4, th = tid&15;
    float e0 = Em[(2*th)*32 + u], e1 = Em[(2*th+1)*32 + u];
    float mx = fmaxf(e0, e1);
    #pragma unroll
    for (int mask=1; mask<16; mask<<=1) mx = fmaxf(mx, __shfl_xor(mx, mask));
    float x0 = expf(e0-mx), x1 = expf(e1-mx);
    float s = x0 + x1;
    #pragma unroll
    for (int mask=1; mask<16; mask<<=1) s += __shfl_xor(s, mask);
    float inv = 1.f/s;
    sm[(2*th)*32 + u]   = x0*inv;
    sm[(2*th+1)*32 + u] = x1*inv;
  }
  __syncthreads();
  {
    int u = tid>>4, th = tid&15;
    float pw = fmaf(sm[u*32 + 2*th], W1[2*th], sm[u*32 + 2*th+1]*W1[2*th+1]);
    #pragma unroll
    for (int mask=1; mask<16; mask<<=1) pw += __shfl_xor(pw, mask);
    if (th==0) w1e[u] = pw;
  }
  __syncthreads();
  for (int idx=tid; idx<704; idx+=512){
    int n = idx>>5, f = idx&31; float a=0.f;
    for (int u=0;u<32;u++) a = fmaf(xb[n*1024+f*32+u], w1e[u], a);
    lhsS[idx]=a;
  }
  __syncthreads();
  for (int idx=tid; idx<704; idx+=512){
    int n = idx>>5, t = idx&31; float a=0.f;
    for (int f=0;f<32;f++) a = fmaf(lhsS[n*32+f], W2[f*32+t], a);
    lhs2[idx]=a;
  }
  for (int idx=tid; idx<704; idx+=512){
    int mm = idx>>5, t = idx&31; float a=0.f;
    for (int u=0;u<32;u++) a = fmaf(xw3[mm*32+u], sm[u*32+t], a);
    rhsS[idx]=a;
  }
  __syncthreads();
  for (int idx=tid; idx<484; idx+=512){
    int a_ = idx/22, l = idx - (idx/22)*22; float p=0.f;
    for (int t=0;t<32;t++) p = fmaf(lhs2[a_*32+t], rhsS[l*32+t], p);
    sig2[idx] = sigm(p + bs[idx]);
  }
  __syncthreads();
  for (int idx=tid; idx<484; idx+=512){
    int n = idx/22, l = idx - (idx/22)*22; float s=0.f;
    for (int mm=0;mm<22;mm++) s = fmaf(Vs[n*22+mm], sig2[mm*22+l], s);
    Sl[idx]=s;
  }
  __syncthreads();
  {
    int grp = tid>>5, nn = tid&31;
    for (int l = grp; l < 22; l += 16){
      float v = (nn<22) ? Sl[nn*22 + l] : -1e30f;
      float mx = v;
      #pragma unroll
      for (int mask=1; mask<32; mask<<=1) mx = fmaxf(mx, __shfl_xor(mx, mask));
      float e = (nn<22) ? expf(v-mx) : 0.f;
      float s = e;
      #pragma unroll
      for (int mask=1; mask<32; mask<<=1) s += __shfl_xor(s, mask);
      if (nn<22) snorm[(size_t)b*484 + nn*22 + l] = e*(1.f/s);
    }
  }
}

// ---------------- Fused m-pair (32x32x16 MFMA, reg-prefetched weights) ----
// Phase A: float4 x loads (thread owns f, t-quad), XOR-swizzled transposed LDS writes.
// Phase B/C read with matching (row>>2) XOR key. Weight fragments prefetched into
// registers: thA at kernel entry (hides under Phase A), wA before the B->C barrier
// (the barrier's vmcnt drain completes them exactly when Phase C starts).
__global__ __launch_bounds__(256, 3) void k_fused(
    const float* __restrict__ x,
    const float* __restrict__ wsT, const float* __restrict__ snorm,
    const u16* __restrict__ thA, const u16* __restrict__ wA, const float* __restrict__ wsB,
    const float* __restrict__ lng, const float* __restrict__ lnb,
    float* __restrict__ out){
  __shared__ __align__(16) u16 GtU[2][32*72];   // G^T bf16 [t][8 col-blocks of 8], stride 72
  __shared__ __align__(16) u16 sgTU[2][34*72];  // sg^T bf16 [t+1][c], rows 0,33 zero
  __shared__ __align__(16) u16 xTU[2][32*40];   // x[m]^T bf16 [t][4 col-blocks of 8], stride 40
  __shared__ __align__(16) float ak4[22*4];     // [n][mi*2+k1]
  __shared__ float smm[2];

  int wg = blockIdx.x;
  int logical = (wg & 7)*1408 + (wg >> 3);      // 11264 = 8*1408 XCD swizzle
  int b = logical/11, mp = logical - b*11;
  int m0 = mp*2;
  int tid = threadIdx.x;
  const float* xb = x + (size_t)b*22528;

  int w = tid>>6, l = tid&63, hi = l>>5, lt = l&31;
  int mi_w = w>>1, ch = w&1;

  // ---- prefetch Phase B weight fragments (latency hides under Phase A) ----
  short8 a_th[6];
  #pragma unroll
  for (int fb=0; fb<6; ++fb)
    a_th[fb] = *(const short8*)(thA + (size_t)(fb*2+ch)*512 + l*8);

  if (tid < 128){                                // zero sg pad rows 0, 33
    int mi = tid>>6, c = tid&63;
    sgTU[mi][c] = 0;
    sgTU[mi][33*72 + c] = 0;
  }
  if (tid < 88){
    int n = tid>>2, j = tid&3;                  // j = mi*2 + k1
    int mi = j>>1, k1 = j&1;
    int m = m0 + mi;
    ak4[tid] = wsT[k1*484 + n*22 + m] * snorm[(size_t)b*484 + n*22 + m];
  }
  if (tid < 2) smm[tid] = snorm[(size_t)b*484 + (m0+tid)*23];
  __syncthreads();

  // ---- Phase A: G[k1][f][t] = sum_n ak*x ; float4 loads, swizzled b16 writes ----
  {
    f32x2 acc[4][2];                             // [mi*2+k1][half]
    #pragma unroll
    for (int j=0;j<4;j++){ acc[j][0]=f32x2{0,0}; acc[j][1]=f32x2{0,0}; }
    const float4* x4 = (const float4*)xb;
    #pragma unroll 2
    for (int n=0;n<22;n++){
      float4 av = *(const float4*)&ak4[n*4];
      float4 xv = x4[n*256 + tid];
      f32x2 xlo = {xv.x, xv.y}, xhi2 = {xv.z, xv.w};
      f32x2 c0 = {av.x,av.x}, c1 = {av.y,av.y}, c2 = {av.z,av.z}, c3 = {av.w,av.w};
      acc[0][0] = __builtin_elementwise_fma(c0, xlo,  acc[0][0]);
      acc[0][1] = __builtin_elementwise_fma(c0, xhi2, acc[0][1]);
      acc[1][0] = __builtin_elementwise_fma(c1, xlo,  acc[1][0]);
      acc[1][1] = __builtin_elementwise_fma(c1, xhi2, acc[1][1]);
      acc[2][0] = __builtin_elementwise_fma(c2, xlo,  acc[2][0]);
      acc[2][1] = __builtin_elementwise_fma(c2, xhi2, acc[2][1]);
      acc[3][0] = __builtin_elementwise_fma(c3, xlo,  acc[3][0]);
      acc[3][1] = __builtin_elementwise_fma(c3, xhi2, acc[3][1]);
    }
    int f = tid>>3, t7 = tid&7, t0 = t7*4;
    int w4 = f>>3, f_low = f&7;
    // swizzled col starts: GtU block (k1*4+w4)^t7 ; xTU block w4^(t7&3)
    int gcol0 = 8*((0*4 + w4) ^ t7) + f_low;
    int gcol1 = 8*((1*4 + w4) ^ t7) + f_low;
    int xcol  = 8*(w4 ^ (t7&3)) + f_low;
    #pragma unroll
    for (int mi=0;mi<2;mi++){
      float4 xm = ((const float4*)xb)[(m0+mi)*256 + tid];
      u16* xd = &xTU[mi][0];
      xd[(t0+0)*40 + xcol] = f2bf(xm.x);
      xd[(t0+1)*40 + xcol] = f2bf(xm.y);
      xd[(t0+2)*40 + xcol] = f2bf(xm.z);
      xd[(t0+3)*40 + xcol] = f2bf(xm.w);
      #pragma unroll
      for (int k1=0;k1<2;k1++){
        int j = mi*2 + k1;
        int gc = k1 ? gcol1 : gcol0;
        u16* gd = &GtU[mi][gc];
        gd[(t0+0)*72] = f2bf(acc[j][0][0]);
        gd[(t0+1)*72] = f2bf(acc[j][0][1]);
        gd[(t0+2)*72] = f2bf(acc[j][1][0]);
        gd[(t0+3)*72] = f2bf(acc[j][1][1]);
      }
    }
  }
  __syncthreads();

  int key8 = lt>>2;            // 0..7, GtU read swizzle key
  int key4 = key8 & 3;         // xTU read swizzle key

  // ---- Phase B: sg[c][t] = relu( Theta12^T G + smm * Theta0^T x ), c-half = ch ----
  {
    f32x16 aG, aX;
    #pragma unroll
    for (int i=0;i<16;i++){ aG[i]=0.f; aX[i]=0.f; }
    const u16* gBase = &GtU[mi_w][lt*72];
    const u16* xBase = &xTU[mi_w][lt*40];
    #pragma unroll
    for (int fb=0; fb<4; ++fb){
      const short8* gp = (const short8*)(gBase + 8*((2*fb+hi)^key8));
      aG = __builtin_amdgcn_mfma_f32_32x32x16_bf16(a_th[fb], *gp, aG, 0,0,0);
    }
    #pragma unroll
    for (int fb=4; fb<6; ++fb){
      const short8* xp = (const short8*)(xBase + 8*((2*(fb-4)+hi)^key4));
      aX = __builtin_amdgcn_mfma_f32_32x32x16_bf16(a_th[fb], *xp, aX, 0,0,0);
    }
    float smv = smm[mi_w];
    u16* srow = &sgTU[mi_w][(1+lt)*72 + ch*32 + 4*hi];
    #pragma unroll
    for (int q=0;q<4;q++){
      float v0 = fmaxf(fmaf(smv, aX[4*q+0], aG[4*q+0]), 0.f);
      float v1 = fmaxf(fmaf(smv, aX[4*q+1], aG[4*q+1]), 0.f);
      float v2 = fmaxf(fmaf(smv, aX[4*q+2], aG[4*q+2]), 0.f);
      float v3 = fmaxf(fmaf(smv, aX[4*q+3], aG[4*q+3]), 0.f);
      uint2 pv; pv.x = f2bf2(v0,v1); pv.y = f2bf2(v2,v3);
      *(uint2*)&srow[8*q] = pv;
    }
  }

  // ---- prefetch Phase C weight fragments; barrier drain lands them for Phase C ----
  short8 wk[14];
  #pragma unroll
  for (int kb=0; kb<14; ++kb)
    wk[kb] = *(const short8*)(wA + (size_t)(kb*2+ch)*512 + l*8);
  __syncthreads();

  // ---- Phase C: y[o][t] = sum_k W[k][o]*B[k][t], K=224, o-half = ch ----
  f32x16 acc;
  #pragma unroll
  for (int i=0;i<16;i++) acc[i]=0.f;
  {
    #pragma unroll
    for (int kb=0; kb<12; ++kb){
      int dt = kb>>2, cq = kb&3;
      const short8* Bp = (const short8*)&sgTU[mi_w][(lt+dt)*72 + cq*16 + 8*hi];
      acc = __builtin_amdgcn_mfma_f32_32x32x16_bf16(wk[kb], *Bp, acc, 0,0,0);
    }
    #pragma unroll
    for (int kb=12; kb<14; ++kb){
      const short8* Bp = (const short8*)&xTU[mi_w][lt*40 + 8*((2*(kb-12)+hi)^key4)];
      acc = __builtin_amdgcn_mfma_f32_32x32x16_bf16(wk[kb], *Bp, acc, 0,0,0);
    }
  }

  // ---- Epilogue: bias + relu + LN over o (64) per t ----
  float y[16];
  float s1 = 0.f, s2 = 0.f;
  {
    const float4* wsB4 = (const float4*)wsB;
    #pragma unroll
    for (int q=0;q<4;q++){
      float4 bq = wsB4[8*ch + 2*q + hi];
      float bb[4] = {bq.x, bq.y, bq.z, bq.w};
      #pragma unroll
      for (int e=0;e<4;e++){
        float v = fmaxf(acc[4*q+e] + bb[e], 0.f);
        y[4*q+e] = v;
        s1 += v;
        s2 = fmaf(v, v, s2);
      }
    }
  }
  s1 += __shfl_xor(s1, 32);
  s2 += __shfl_xor(s2, 32);
  float* p1 = (float*)&GtU[0][0];    // overlay (GtU dead after Phase B barrier)
  float* p2 = p1 + 128;
  if (l < 32){
    p1[(mi_w*32 + lt)*2 + ch] = s1;
    p2[(mi_w*32 + lt)*2 + ch] = s2;
  }
  __syncthreads();
  f32x2 q1 = *(const f32x2*)&p1[(mi_w*32 + lt)*2];
  f32x2 q2 = *(const f32x2*)&p2[(mi_w*32 + lt)*2];
  float S1 = q1[0] + q1[1], S2 = q2[0] + q2[1];
  float mu = S1*(1.f/64.f);
  float var = S2*(1.f/64.f) - mu*mu;
  float rs = rsqrtf(var + 1e-5f);
  {
    const float4* lng4 = (const float4*)lng;
    const float4* lnb4 = (const float4*)lnb;
    float* ob = out + ((size_t)(b*22 + m0 + mi_w)*64 + 32*ch)*32;
    #pragma unroll
    for (int q=0;q<4;q++){
      float4 g4 = lng4[8*ch + 2*q + hi];
      float4 b4 = lnb4[8*ch + 2*q + hi];
      float gg[4] = {g4.x,g4.y,g4.z,g4.w};
      float bg[4] = {b4.x,b4.y,b4.z,b4.w};
      #pragma unroll
      for (int e=0;e<4;e++){
        int orow = 8*q + 4*hi + e;
        ob[orow*32 + lt] = (y[4*q+e]-mu)*rs*gg[e] + bg[e];
      }
    }
  }
}

extern "C" void kernel_launch(void* const* d_in, const int* in_sizes, int n_in,
                              void* d_out, int out_size, void* d_ws, size_t ws_size,
                              hipStream_t stream){
  const float* x     = (const float*)d_in[0];
  const float* U1    = (const float*)d_in[1];
  const float* U2    = (const float*)d_in[2];
  const float* U3    = (const float*)d_in[3];
  const float* be    = (const float*)d_in[4];
  const float* Ve    = (const float*)d_in[5];
  const float* W1    = (const float*)d_in[6];
  const float* W2    = (const float*)d_in[7];
  const float* W3    = (const float*)d_in[8];
  const float* bs    = (const float*)d_in[9];
  const float* Vs    = (const float*)d_in[10];
  const float* Theta = (const float*)d_in[11];
  const float* emb   = (const float*)d_in[12];
  const float* tw    = (const float*)d_in[13];
  const float* tb    = (const float*)d_in[14];
  const float* rw    = (const float*)d_in[15];
  const float* rb    = (const float*)d_in[16];
  const float* lng   = (const float*)d_in[17];
  const float* lnb   = (const float*)d_in[18];
  float* out = (float*)d_out;
  float* wsf = (float*)d_ws;
  float* wsT   = wsf;                        // 968 floats (pad to 1024)
  float* snorm = wsf + 1024;                 // 1024*484 floats
  u16*   thA   = (u16*)(wsf + 496640);       // 6144 u16
  u16*   wA    = (u16*)(wsf + 499712);       // 14336 u16
  float* wsB   = wsf + 506880;               // 64 floats

  k_sup_prep<<<82, 256, 0, stream>>>(emb, wsT, Theta, tw, tb, rw, rb, thA, wA, wsB);
  k_attn<<<1024, 512, 0, stream>>>(x, U1,U2,U3, be,Ve, W1,W2,W3, bs,Vs, snorm);
  k_fused<<<1024*11, 256, 0, stream>>>(x, wsT, snorm, thA, wA, wsB, lng, lnb, out);
}

// Round 9
// 153.918 us; speedup vs baseline: 1.0448x; 1.0249x over previous
//
#include <hip/hip_runtime.h>
#include <hip/hip_bf16.h>
#include <math.h>

// B=1024, N=22, F_IN=32, T=32, K=3, CHEV=64, TIMEF=64
// x[b,n,f,t]: b-stride 22528, n-stride 1024, f-stride 32

typedef unsigned short u16;
typedef __attribute__((ext_vector_type(8))) short short8;
typedef __attribute__((ext_vector_type(4))) float f32x4;
typedef __attribute__((ext_vector_type(2))) float f32x2;

__device__ __forceinline__ float sigm(float v){ return 1.f/(1.f+expf(-v)); }

__device__ __forceinline__ u16 f2bf(float x){
  __hip_bfloat16 h = __float2bfloat16(x);
  return *reinterpret_cast<u16*>(&h);
}
__device__ __forceinline__ unsigned f2bf2(float lo, float hi){
  return (unsigned)f2bf(lo) | ((unsigned)f2bf(hi) << 16);
}

// ---------------- attnA: temporal attention (phases 1-7) -> smG, w1eG, xw3G ----------------
// blocks 0..1023: attention; blocks 1024..1064: weight packing; block 1065: supports
__global__ __launch_bounds__(512) void k_attnA(
    const float* __restrict__ x,
    const float* __restrict__ U1, const float* __restrict__ U2, const float* __restrict__ U3,
    const float* __restrict__ be, const float* __restrict__ Ve, const float* __restrict__ W1,
    const float* __restrict__ W3,
    float* __restrict__ smG, float* __restrict__ w1eG, float* __restrict__ xw3G,
    // prep inputs/outputs:
    const float* __restrict__ emb, float* __restrict__ wsT,
    const float* __restrict__ Theta,
    const float* __restrict__ tw, const float* __restrict__ tb,
    const float* __restrict__ rw, const float* __restrict__ rb,
    u16* __restrict__ thA, u16* __restrict__ wA, float* __restrict__ wsB){
  __shared__ float xu1[1024];
  __shared__ float rhs_t[704];
  __shared__ float lhs_t[704];
  __shared__ float sigp[1024];
  __shared__ float Em[1024];
  __shared__ float sm[1024];
  __shared__ float xw3[704];
  __shared__ float w1e[32];

  int bid = blockIdx.x, tid = threadIdx.x;

  if (bid >= 1024){
    int pb = bid - 1024;
    if (pb < 41){
      // 16x16-fragment weight packing (R5 layout)
      int t2 = pb*512 + tid;
      if (t2 < 6144){
        int j = t2&7, l = (t2>>3)&63, blk = t2>>9;       // blk 0..11
        int ks = blk>>2, ci = blk&3, r = l&15, g = l>>4;
        int kf = 32*ks + 8*g + j, c = 16*ci + r;
        thA[t2] = f2bf(Theta[kf*64 + c]);
      } else if (t2 < 20480){
        int e = t2 - 6144;
        int j = e&7, l = (e>>3)&63, blk = e>>9;          // blk 0..27
        int ks = blk>>2, oi = blk&3, r = l&15, g = l>>4;
        int k = 32*ks + 8*g + j, o = 16*oi + r;
        float v = (k < 192) ? tw[o*192 + (k&63)*3 + (k>>6)] : rw[o*32 + (k-192)];
        wA[e] = f2bf(v);
      } else if (t2 < 20544){
        int o = t2 - 20480; wsB[o] = tb[o] + rb[o];
      }
      return;
    }
    // supports block (alias LDS)
    float* M   = &xu1[0];
    float* T1s = &sigp[0];
    for (int idx=tid; idx<484; idx+=512){
      int n = idx/22, m = idx - (idx/22)*22;
      float s = 0.f;
      for (int j=0;j<22;j++) s += emb[n*22+j]*emb[m*22+j];
      M[idx] = fmaxf(s, 0.f);
    }
    __syncthreads();
    if (tid < 22){
      float mx = -1e30f;
      for (int m=0;m<22;m++) mx = fmaxf(mx, M[tid*22+m]);
      float s = 0.f;
      for (int m=0;m<22;m++) s += expf(M[tid*22+m]-mx);
      float inv = 1.f/s;
      for (int m=0;m<22;m++) T1s[tid*22+m] = expf(M[tid*22+m]-mx)*inv;
    }
    __syncthreads();
    for (int idx=tid; idx<484; idx+=512){
      int n = idx/22, m = idx - (idx/22)*22;
      float s = 0.f;
      for (int p=0;p<22;p++) s += T1s[n*22+p]*T1s[p*22+m];
      wsT[idx]      = T1s[idx];
      wsT[484+idx]  = 2.f*s - ((n==m)?1.f:0.f);
    }
    return;
  }

  int b = bid;
  const float* xb = x + (size_t)b*22528;

  for (int idx=tid; idx<1024; idx+=512){
    float a=0.f;
    for (int n=0;n<22;n++) a = fmaf(xb[n*1024 + idx], U1[n], a);
    xu1[idx]=a;
  }
  for (int idx=tid; idx<704; idx+=512){
    int n = idx>>5, t = idx&31; float a=0.f, c=0.f;
    for (int f=0;f<32;f++){ float xv = xb[n*1024+f*32+t]; a = fmaf(U3[f],xv,a); c = fmaf(W3[f],xv,c); }
    rhs_t[idx]=a; xw3[idx]=c;
  }
  __syncthreads();
  for (int idx=tid; idx<704; idx+=512){
    int t = idx/22, n2 = idx - t*22; float a=0.f;
    for (int f=0;f<32;f++) a = fmaf(xu1[f*32+t], U2[f*22+n2], a);
    lhs_t[idx]=a;
  }
  __syncthreads();
  for (int idx=tid; idx<1024; idx+=512){
    int s = idx>>5, u = idx&31; float p=0.f;
    for (int n=0;n<22;n++) p = fmaf(lhs_t[s*22+n], rhs_t[n*32+u], p);
    sigp[idx] = sigm(p + be[idx]);
  }
  __syncthreads();
  for (int idx=tid; idx<1024; idx+=512){
    int t = idx>>5, u = idx&31; float a=0.f;
    for (int s2=0;s2<32;s2++) a = fmaf(Ve[t*32+s2], sigp[s2*32+u], a);
    Em[idx]=a;
  }
  __syncthreads();
  {
    int u = tid>>4, th = tid&15;
    float e0 = Em[(2*th)*32 + u], e1 = Em[(2*th+1)*32 + u];
    float mx = fmaxf(e0, e1);
    #pragma unroll
    for (int mask=1; mask<16; mask<<=1) mx = fmaxf(mx, __shfl_xor(mx, mask));
    float x0 = expf(e0-mx), x1 = expf(e1-mx);
    float s = x0 + x1;
    #pragma unroll
    for (int mask=1; mask<16; mask<<=1) s += __shfl_xor(s, mask);
    float inv = 1.f/s;
    sm[(2*th)*32 + u]   = x0*inv;
    sm[(2*th+1)*32 + u] = x1*inv;
  }
  __syncthreads();
  {
    int u = tid>>4, th = tid&15;
    float pw = fmaf(sm[u*32 + 2*th], W1[2*th], sm[u*32 + 2*th+1]*W1[2*th+1]);
    #pragma unroll
    for (int mask=1; mask<16; mask<<=1) pw += __shfl_xor(pw, mask);
    if (th==0) w1e[u] = pw;
  }
  __syncthreads();
  // store sm, w1e, xw3 for attnB
  for (int idx=tid; idx<1024; idx+=512) smG[(size_t)b*1024 + idx] = sm[idx];
  for (int idx=tid; idx<704; idx+=512)  xw3G[(size_t)b*704 + idx] = xw3[idx];
  if (tid < 32) w1eG[b*32 + tid] = w1e[tid];
}

// ---------------- attnB: spatial attention (phases 8-13) -> snorm ----------------
__global__ __launch_bounds__(512) void k_attnB(
    const float* __restrict__ x,
    const float* __restrict__ W2, const float* __restrict__ bs, const float* __restrict__ Vs,
    const float* __restrict__ smG, const float* __restrict__ w1eG, const float* __restrict__ xw3G,
    float* __restrict__ snorm){
  __shared__ float sm[1024];
  __shared__ float xw3[704];
  __shared__ float w1e[32];
  __shared__ float lhsS[704];
  __shared__ float lhs2[704];
  __shared__ float rhsS[704];
  __shared__ float sig2[484];
  __shared__ float Sl[484];

  int b = blockIdx.x, tid = threadIdx.x;
  const float* xb = x + (size_t)b*22528;

  for (int idx=tid; idx<1024; idx+=512) sm[idx] = smG[(size_t)b*1024 + idx];
  for (int idx=tid; idx<704; idx+=512)  xw3[idx] = xw3G[(size_t)b*704 + idx];
  if (tid < 32) w1e[tid] = w1eG[b*32 + tid];
  __syncthreads();

  // phase 8: lhsS[n,f] = sum_u x[n,f,u]*w1e[u]  (vectorized float4 over u)
  for (int idx=tid; idx<704; idx+=512){
    int n = idx>>5, f = idx&31;
    const float4* xp = (const float4*)(xb + n*1024 + f*32);
    const float4* wv = (const float4*)w1e;
    float a = 0.f;
    #pragma unroll
    for (int q=0;q<8;q++){
      float4 xv = xp[q], w4 = wv[q];
      a = fmaf(xv.x, w4.x, a); a = fmaf(xv.y, w4.y, a);
      a = fmaf(xv.z, w4.z, a); a = fmaf(xv.w, w4.w, a);
    }
    lhsS[idx]=a;
  }
  __syncthreads();
  for (int idx=tid; idx<704; idx+=512){
    int n = idx>>5, t = idx&31; float a=0.f;
    for (int f=0;f<32;f++) a = fmaf(lhsS[n*32+f], W2[f*32+t], a);
    lhs2[idx]=a;
  }
  for (int idx=tid; idx<704; idx+=512){
    int mm = idx>>5, t = idx&31; float a=0.f;
    for (int u=0;u<32;u++) a = fmaf(xw3[mm*32+u], sm[u*32+t], a);
    rhsS[idx]=a;
  }
  __syncthreads();
  for (int idx=tid; idx<484; idx+=512){
    int a_ = idx/22, l = idx - (idx/22)*22; float p=0.f;
    for (int t=0;t<32;t++) p = fmaf(lhs2[a_*32+t], rhsS[l*32+t], p);
    sig2[idx] = sigm(p + bs[idx]);
  }
  __syncthreads();
  for (int idx=tid; idx<484; idx+=512){
    int n = idx/22, l = idx - (idx/22)*22; float s=0.f;
    for (int mm=0;mm<22;mm++) s = fmaf(Vs[n*22+mm], sig2[mm*22+l], s);
    Sl[idx]=s;
  }
  __syncthreads();
  {
    int grp = tid>>5, nn = tid&31;
    for (int l = grp; l < 22; l += 16){
      float v = (nn<22) ? Sl[nn*22 + l] : -1e30f;
      float mx = v;
      #pragma unroll
      for (int mask=1; mask<32; mask<<=1) mx = fmaxf(mx, __shfl_xor(mx, mask));
      float e = (nn<22) ? expf(v-mx) : 0.f;
      float s = e;
      #pragma unroll
      for (int mask=1; mask<32; mask<<=1) s += __shfl_xor(s, mask);
      if (nn<22) snorm[(size_t)b*484 + nn*22 + l] = e*(1.f/s);
    }
  }
}

// ---------------- Fused m-pair (R5 16x16 version, best measured) ----------------
__global__ __launch_bounds__(256, 6) void k_fused(
    const float* __restrict__ x,
    const float* __restrict__ wsT, const float* __restrict__ snorm,
    const u16* __restrict__ thA, const u16* __restrict__ wA, const float* __restrict__ wsB,
    const float* __restrict__ lng, const float* __restrict__ lnb,
    float* __restrict__ out){
  __shared__ __align__(16) u16 GtU[2][32*72];   // G^T bf16 [t][64 cols], stride 72, swizzled blocks
  __shared__ __align__(16) u16 sgTU[2][34*72];  // sg^T bf16 [t+1][c], rows 0,33 zero
  __shared__ __align__(16) u16 xTU[2][32*40];   // x[m]^T bf16 [t][f], stride 40, swizzled blocks
  __shared__ __align__(16) float ak4[22*4];     // [n][mi*2+k1]
  __shared__ float smm[2];

  int wg = blockIdx.x;
  int logical = (wg & 7)*1408 + (wg >> 3);      // 11264 = 8*1408 XCD swizzle
  int b = logical/11, mp = logical - b*11;
  int m0 = mp*2;
  int tid = threadIdx.x;
  const float* xb = x + (size_t)b*22528;

  if (tid < 128){                                // zero sg pad rows 0, 33
    int mi = tid>>6, r6 = tid&63;
    int row = (r6>>5) ? 33 : 0, c2 = r6&31;
    *(unsigned*)&sgTU[mi][row*72 + c2*2] = 0u;
  }
  if (tid < 88){
    int n = tid>>2, j = tid&3;                  // j = mi*2 + k1
    int mi = j>>1, k1 = j&1;
    int m = m0 + mi;
    ak4[tid] = wsT[k1*484 + n*22 + m] * snorm[(size_t)b*484 + n*22 + m];
  }
  if (tid < 2) smm[tid] = snorm[(size_t)b*484 + (m0+tid)*23];
  __syncthreads();

  // ---- Phase A: float4 loads, XOR-swizzled transposed b16 writes ----
  {
    f32x2 acc[4][2];
    #pragma unroll
    for (int j=0;j<4;j++){ acc[j][0]=f32x2{0,0}; acc[j][1]=f32x2{0,0}; }
    const float4* x4 = (const float4*)xb;
    #pragma unroll 2
    for (int n=0;n<22;n++){
      float4 av = *(const float4*)&ak4[n*4];
      float4 xv = x4[n*256 + tid];
      f32x2 xlo = {xv.x, xv.y}, xhi2 = {xv.z, xv.w};
      f32x2 c0 = {av.x,av.x}, c1 = {av.y,av.y}, c2 = {av.z,av.z}, c3 = {av.w,av.w};
      acc[0][0] = __builtin_elementwise_fma(c0, xlo,  acc[0][0]);
      acc[0][1] = __builtin_elementwise_fma(c0, xhi2, acc[0][1]);
      acc[1][0] = __builtin_elementwise_fma(c1, xlo,  acc[1][0]);
      acc[1][1] = __builtin_elementwise_fma(c1, xhi2, acc[1][1]);
      acc[2][0] = __builtin_elementwise_fma(c2, xlo,  acc[2][0]);
      acc[2][1] = __builtin_elementwise_fma(c2, xhi2, acc[2][1]);
      acc[3][0] = __builtin_elementwise_fma(c3, xlo,  acc[3][0]);
      acc[3][1] = __builtin_elementwise_fma(c3, xhi2, acc[3][1]);
    }
    int f = tid>>3, t7 = tid&7, t0 = t7*4;
    int w4 = f>>3, f_low = f&7;
    int gcol0 = 8*((0*4 + w4) ^ t7) + f_low;
    int gcol1 = 8*((1*4 + w4) ^ t7) + f_low;
    int xcol  = 8*(w4 ^ (t7&3)) + f_low;
    #pragma unroll
    for (int mi=0;mi<2;mi++){
      float4 xm = ((const float4*)xb)[(m0+mi)*256 + tid];
      u16* xd = &xTU[mi][0];
      xd[(t0+0)*40 + xcol] = f2bf(xm.x);
      xd[(t0+1)*40 + xcol] = f2bf(xm.y);
      xd[(t0+2)*40 + xcol] = f2bf(xm.z);
      xd[(t0+3)*40 + xcol] = f2bf(xm.w);
      #pragma unroll
      for (int k1=0;k1<2;k1++){
        int j = mi*2 + k1;
        int gc = k1 ? gcol1 : gcol0;
        u16* gd = &GtU[mi][gc];
        gd[(t0+0)*72] = f2bf(acc[j][0][0]);
        gd[(t0+1)*72] = f2bf(acc[j][0][1]);
        gd[(t0+2)*72] = f2bf(acc[j][1][0]);
        gd[(t0+3)*72] = f2bf(acc[j][1][1]);
      }
    }
  }
  __syncthreads();

  int w = tid>>6, l = tid&63, r = l&15, g = l>>4;

  // ---- Phase B: sg = relu( Theta12^T G + smm * Theta0^T x ) ----
  {
    const u16* tA = thA + (size_t)(w*64 + l)*8;
    short8 a0 = *(const short8*)(tA);
    short8 a1 = *(const short8*)(tA + 2048);
    short8 a2 = *(const short8*)(tA + 4096);
    #pragma unroll
    for (int mi=0;mi<2;mi++){
      float sm_ = smm[mi];
      #pragma unroll
      for (int ti=0; ti<2; ++ti){
        int row = ti*16 + r;
        int h  = (row>>2)&7;
        int h2 = (row>>2)&3;
        f32x4 a12 = {0.f,0.f,0.f,0.f}, ax = {0.f,0.f,0.f,0.f};
        const u16* gp0 = &GtU[mi][row*72 + 8*((0*4+g)^h)];
        const u16* gp1 = &GtU[mi][row*72 + 8*((1*4+g)^h)];
        a12 = __builtin_amdgcn_mfma_f32_16x16x32_bf16(a1, *(const short8*)(gp0), a12, 0,0,0);
        a12 = __builtin_amdgcn_mfma_f32_16x16x32_bf16(a2, *(const short8*)(gp1), a12, 0,0,0);
        const u16* xp = &xTU[mi][row*40 + 8*(g^h2)];
        ax  = __builtin_amdgcn_mfma_f32_16x16x32_bf16(a0, *(const short8*)(xp),  ax,  0,0,0);
        int orow = 1 + row, c0 = w*16 + g*4;
        float v0 = fmaxf(fmaf(sm_, ax[0], a12[0]), 0.f);
        float v1 = fmaxf(fmaf(sm_, ax[1], a12[1]), 0.f);
        float v2 = fmaxf(fmaf(sm_, ax[2], a12[2]), 0.f);
        float v3 = fmaxf(fmaf(sm_, ax[3], a12[3]), 0.f);
        *(unsigned*)&sgTU[mi][orow*72 + c0]     = f2bf2(v0, v1);
        *(unsigned*)&sgTU[mi][orow*72 + c0 + 2] = f2bf2(v2, v3);
      }
    }
  }
  __syncthreads();

  // ---- Phase C: y[o][t] = sum_k W[k][o]*B[k][t], K=224 ----
  f32x4 acc[2][2];
  acc[0][0]=f32x4{0,0,0,0}; acc[0][1]=f32x4{0,0,0,0};
  acc[1][0]=f32x4{0,0,0,0}; acc[1][1]=f32x4{0,0,0,0};
  {
    const u16* pA = wA + (size_t)(w*64 + l)*8;
    #pragma unroll
    for (int ks=0; ks<6; ++ks){
      short8 wk = *(const short8*)(pA + ks*2048);
      int seg = ks>>1, colb = (ks&1)*32 + 8*g;
      #pragma unroll
      for (int mi=0;mi<2;mi++){
        const u16* q0 = &sgTU[mi][(r + seg)*72 + colb];
        acc[mi][0] = __builtin_amdgcn_mfma_f32_16x16x32_bf16(wk, *(const short8*)(q0),         acc[mi][0], 0,0,0);
        acc[mi][1] = __builtin_amdgcn_mfma_f32_16x16x32_bf16(wk, *(const short8*)(q0 + 16*72), acc[mi][1], 0,0,0);
      }
    }
    short8 wk = *(const short8*)(pA + 6*2048);
    int h2 = (r>>2)&3;
    #pragma unroll
    for (int mi=0;mi<2;mi++){
      const u16* q = &xTU[mi][r*40 + 8*(g^h2)];
      acc[mi][0] = __builtin_amdgcn_mfma_f32_16x16x32_bf16(wk, *(const short8*)(q),         acc[mi][0], 0,0,0);
      acc[mi][1] = __builtin_amdgcn_mfma_f32_16x16x32_bf16(wk, *(const short8*)(q + 16*40), acc[mi][1], 0,0,0);
    }
  }

  // ---- Epilogue: bias + relu + LN over o per t, both m ----
  float4 bias4 = ((const float4*)wsB)[w*4 + g];
  float bb[4] = {bias4.x, bias4.y, bias4.z, bias4.w};
  float y[2][2][4];
  float s1[2][2] = {{0.f,0.f},{0.f,0.f}}, s2[2][2] = {{0.f,0.f},{0.f,0.f}};
  #pragma unroll
  for (int mi=0;mi<2;mi++){
    #pragma unroll
    for (int h=0;h<2;h++){
      #pragma unroll
      for (int i=0;i<4;i++){
        float v = fmaxf(acc[mi][h][i] + bb[i], 0.f);
        y[mi][h][i] = v;
        s1[mi][h] += v;
        s2[mi][h] = fmaf(v, v, s2[mi][h]);
      }
      s1[mi][h] += __shfl_xor(s1[mi][h],16); s1[mi][h] += __shfl_xor(s1[mi][h],32);
      s2[mi][h] += __shfl_xor(s2[mi][h],16); s2[mi][h] += __shfl_xor(s2[mi][h],32);
    }
  }
  float* p1 = (float*)&GtU[0][0];
  float* p2 = p1 + 256;
  if (l < 16){
    #pragma unroll
    for (int mi=0;mi<2;mi++){
      p1[(mi*32 + l)*4 + w]      = s1[mi][0];
      p1[(mi*32 + 16 + l)*4 + w] = s1[mi][1];
      p2[(mi*32 + l)*4 + w]      = s2[mi][0];
      p2[(mi*32 + 16 + l)*4 + w] = s2[mi][1];
    }
  }
  __syncthreads();
  float4 g4 = ((const float4*)lng)[w*4 + g];
  float4 b4 = ((const float4*)lnb)[w*4 + g];
  float gg[4]={g4.x,g4.y,g4.z,g4.w}, bgg[4]={b4.x,b4.y,b4.z,b4.w};
  #pragma unroll
  for (int mi=0;mi<2;mi++){
    float4 q1a = ((const float4*)p1)[mi*32 + r],      q2a = ((const float4*)p2)[mi*32 + r];
    float4 q1b = ((const float4*)p1)[mi*32 + 16 + r], q2b = ((const float4*)p2)[mi*32 + 16 + r];
    float S1a = q1a.x+q1a.y+q1a.z+q1a.w, S2a = q2a.x+q2a.y+q2a.z+q2a.w;
    float S1b = q1b.x+q1b.y+q1b.z+q1b.w, S2b = q2b.x+q2b.y+q2b.z+q2b.w;
    float mu0 = S1a*(1.f/64.f), var0 = S2a*(1.f/64.f) - mu0*mu0, rs0 = rsqrtf(var0 + 1e-5f);
    float mu1 = S1b*(1.f/64.f), var1 = S2b*(1.f/64.f) - mu1*mu1, rs1 = rsqrtf(var1 + 1e-5f);
    float* ob = out + ((size_t)(b*22 + m0 + mi)*64 + (w*16 + g*4))*32;
    #pragma unroll
    for (int i=0;i<4;i++){
      ob[i*32 + r]      = (y[mi][0][i]-mu0)*rs0*gg[i] + bgg[i];
      ob[i*32 + 16 + r] = (y[mi][1][i]-mu1)*rs1*gg[i] + bgg[i];
    }
  }
}

extern "C" void kernel_launch(void* const* d_in, const int* in_sizes, int n_in,
                              void* d_out, int out_size, void* d_ws, size_t ws_size,
                              hipStream_t stream){
  const float* x     = (const float*)d_in[0];
  const float* U1    = (const float*)d_in[1];
  const float* U2    = (const float*)d_in[2];
  const float* U3    = (const float*)d_in[3];
  const float* be    = (const float*)d_in[4];
  const float* Ve    = (const float*)d_in[5];
  const float* W1    = (const float*)d_in[6];
  const float* W2    = (const float*)d_in[7];
  const float* W3    = (const float*)d_in[8];
  const float* bs    = (const float*)d_in[9];
  const float* Vs    = (const float*)d_in[10];
  const float* Theta = (const float*)d_in[11];
  const float* emb   = (const float*)d_in[12];
  const float* tw    = (const float*)d_in[13];
  const float* tb    = (const float*)d_in[14];
  const float* rw    = (const float*)d_in[15];
  const float* rb    = (const float*)d_in[16];
  const float* lng   = (const float*)d_in[17];
  const float* lnb   = (const float*)d_in[18];
  float* out = (float*)d_out;
  float* wsf = (float*)d_ws;
  float* wsT   = wsf;                        // 1024 floats
  float* snorm = wsf + 1024;                 // 495616 floats
  u16*   thA   = (u16*)(wsf + 496640);       // 6144 u16 (3072 floats)
  u16*   wA    = (u16*)(wsf + 499712);       // 14336 u16 (7168 floats)
  float* wsB   = wsf + 506880;               // 64 floats
  float* smG   = wsf + 507904;               // 1024*1024
  float* xw3G  = wsf + 1556480;              // 1024*704
  float* w1eG  = wsf + 2277376;              // 1024*32
                                             // end ~2310144 floats (~9.2 MB)

  k_attnA<<<1066, 512, 0, stream>>>(x, U1,U2,U3, be,Ve, W1, W3, smG, w1eG, xw3G,
                                    emb, wsT, Theta, tw, tb, rw, rb, thA, wA, wsB);
  k_attnB<<<1024, 512, 0, stream>>>(x, W2, bs, Vs, smG, w1eG, xw3G, snorm);
  k_fused<<<1024*11, 256, 0, stream>>>(x, wsT, snorm, thA, wA, wsB, lng, lnb, out);
}